// Round 4
// baseline (13580.223 us; speedup 1.0000x reference)
//
#include <hip/hip_runtime.h>
#include <hip/hip_bf16.h>
#include <cstdint>
#include <cstddef>

#define DEV __device__ __forceinline__

namespace {

constexpr int S    = 2048;
constexpr int D    = 512;
constexpr int H    = 8;
constexpr int DH   = 64;
constexpr int NL   = 6;
constexpr int MLPD = 2048;
constexpr int VOC  = 256;
constexpr int BLKA = 128;   // sparse attention block
constexpr int CCOL = 32;    // fixed2 column count
constexpr float EPSF = 1e-6f;

DEV float gelu_tanh(float x){
  float x3 = x * x * x;
  return 0.5f * x * (1.f + tanhf(0.7978845608028654f * (x + 0.044715f * x3)));
}

// ---------------- embedding + positional (shift-right teacher forcing) -------
__global__ void k_embed(const int* __restrict__ tokens, const float* __restrict__ emb,
                        const float* __restrict__ pos, float* __restrict__ x){
  int s = blockIdx.x;
  int tok = (s == 0) ? 0 : tokens[s - 1];   // shifted = pad-left, drop last
  if (tok < 0) tok = 0; if (tok >= VOC) tok = VOC - 1;  // defensive
  const float* er = emb + (size_t)tok * D;
  const float* pr = pos + (size_t)s * D;
  float* xr = x + (size_t)s * D;
  for (int d = threadIdx.x; d < D; d += blockDim.x)
    xr[d] = er[d] + pr[d];
}

// ---------------- layernorm: one wave per row, fp32 in/out -------------------
__global__ __launch_bounds__(64)
void k_ln(const float* __restrict__ x, const float* __restrict__ sc,
          const float* __restrict__ bi, float* __restrict__ out){
  int s = blockIdx.x, t = threadIdx.x;
  const float* xr = x + (size_t)s * D;
  float v[8]; float sum = 0.f, sq = 0.f;
  #pragma unroll
  for (int e = 0; e < 8; ++e){ v[e] = xr[t + 64 * e]; sum += v[e]; sq += v[e] * v[e]; }
  #pragma unroll
  for (int off = 32; off >= 1; off >>= 1){
    sum += __shfl_down(sum, off, 64);
    sq  += __shfl_down(sq,  off, 64);
  }
  sum = __shfl(sum, 0, 64); sq = __shfl(sq, 0, 64);
  float mu  = sum * (1.f / (float)D);
  float var = sq * (1.f / (float)D) - mu * mu;
  float r = rsqrtf(var + EPSF);
  float* orow = out + (size_t)s * D;
  #pragma unroll
  for (int e = 0; e < 8; ++e){
    int d = t + 64 * e;
    orow[d] = (v[e] - mu) * r * sc[d] + bi[d];
  }
}

// ---------------- naive GEMM: trivially correct. C[m][n] = sum_k A[m][k]B[k][n]
// grid: (ceil(N/256), M/4); block 256. Each thread: one column n, four rows.
// MODE 0: Cf = acc*alpha          MODE 1: Cf = gelu(acc + bias)
// MODE 2: Cf += acc + bias        MODE 3: Cf = acc + bias   (f32 store)
template<int MODE>
__global__ __launch_bounds__(256)
void k_ngemm(const float* __restrict__ A, const float* __restrict__ B,
             const float* __restrict__ bias, float* __restrict__ Cf,
             int M, int N, int K, float alpha)
{
  (void)M;
  int n = blockIdx.x * 256 + threadIdx.x;
  if (n >= N) return;
  int m0 = blockIdx.y * 4;
  const float* a0 = A + (size_t)(m0 + 0) * K;
  const float* a1 = A + (size_t)(m0 + 1) * K;
  const float* a2 = A + (size_t)(m0 + 2) * K;
  const float* a3 = A + (size_t)(m0 + 3) * K;
  const float* bp = B + n;
  float c0 = 0.f, c1 = 0.f, c2 = 0.f, c3 = 0.f;
  for (int k = 0; k < K; ++k){
    float b = bp[(size_t)k * N];
    c0 += a0[k] * b; c1 += a1[k] * b; c2 += a2[k] * b; c3 += a3[k] * b;
  }
  float bb = bias ? bias[n] : 0.f;
  float cc[4] = {c0, c1, c2, c3};
  #pragma unroll
  for (int r = 0; r < 4; ++r){
    size_t idx = (size_t)(m0 + r) * N + n;
    float vv = cc[r] * alpha + bb;
    if (MODE == 1)      Cf[idx] = gelu_tanh(vv);
    else if (MODE == 2) Cf[idx] += vv;
    else                Cf[idx] = vv;   // MODE 0 / 3
  }
}

// ---------------- sparse attention: one thread per (head, query row) ---------
// pattern: own-block causal  U  (j%128 >= 96 for past blocks), & tokens[j]>0.
// Fully-masked row -> reference softmax over constant -1e9 = uniform 1/S.
__global__ __launch_bounds__(64)
void k_attn(const float* __restrict__ q, const float* __restrict__ kM,
            const float* __restrict__ vM, const int* __restrict__ tokens,
            float* __restrict__ o)
{
  int idx = blockIdx.x * 64 + threadIdx.x;
  int h0 = idx >> 11;          // idx / S
  int i  = idx & (S - 1);
  const float* qp = q + (size_t)i * D + h0 * DH;
  float qr[DH];
  #pragma unroll
  for (int d = 0; d < DH; d += 4){
    float4 t4 = *reinterpret_cast<const float4*>(qp + d);
    qr[d] = t4.x; qr[d+1] = t4.y; qr[d+2] = t4.z; qr[d+3] = t4.w;
  }
  float acc[DH] = {};
  float m = -1e30f, l = 0.f;
  int cnt = 0;
  int bi = i >> 7;
  for (int bj = 0; bj <= bi; ++bj){
    int j0 = bj * BLKA + ((bj < bi) ? (BLKA - CCOL) : 0);
    int j1 = (bj < bi) ? (bj * BLKA + BLKA) : (i + 1);
    for (int j = j0; j < j1; ++j){
      if (tokens[j] == 0) continue;           // key padding (unshifted tokens)
      const float* kp = kM + (size_t)j * D + h0 * DH;
      float s = 0.f;
      #pragma unroll
      for (int d = 0; d < DH; d += 4){
        float4 k4 = *reinterpret_cast<const float4*>(kp + d);
        s += qr[d]*k4.x + qr[d+1]*k4.y + qr[d+2]*k4.z + qr[d+3]*k4.w;
      }
      float mn = fmaxf(m, s);
      float c = __expf(m - mn);
      float p = __expf(s - mn);
      l = l * c + p;
      const float* vp = vM + (size_t)j * D + h0 * DH;
      #pragma unroll
      for (int d = 0; d < DH; d += 4){
        float4 v4 = *reinterpret_cast<const float4*>(vp + d);
        acc[d]   = acc[d]  *c + p*v4.x;
        acc[d+1] = acc[d+1]*c + p*v4.y;
        acc[d+2] = acc[d+2]*c + p*v4.z;
        acc[d+3] = acc[d+3]*c + p*v4.w;
      }
      m = mn; ++cnt;
    }
  }
  if (cnt == 0){
    // reference: softmax over all -1e9 = uniform over ALL S positions
    for (int j = 0; j < S; ++j){
      const float* vp = vM + (size_t)j * D + h0 * DH;
      #pragma unroll
      for (int d = 0; d < DH; d += 4){
        float4 v4 = *reinterpret_cast<const float4*>(vp + d);
        acc[d] += v4.x; acc[d+1] += v4.y; acc[d+2] += v4.z; acc[d+3] += v4.w;
      }
    }
    l = (float)S;
  }
  float inv = 1.f / l;
  float* op = o + (size_t)i * D + h0 * DH;
  #pragma unroll
  for (int d = 0; d < DH; d += 4){
    float4 r4 = make_float4(acc[d]*inv, acc[d+1]*inv, acc[d+2]*inv, acc[d+3]*inv);
    *reinterpret_cast<float4*>(op + d) = r4;
  }
}

} // anonymous namespace

extern "C" void kernel_launch(void* const* d_in, const int* in_sizes, int n_in,
                              void* d_out, int out_size, void* d_ws, size_t ws_size,
                              hipStream_t stream)
{
  (void)n_in; (void)out_size; (void)ws_size;

  // input-order detection: tokens is the only 2048-element input; dict order
  // puts it at slot 0. (Confirmed triggered-false on this harness; kept as
  // cheap insurance.)
  int I_tok=0, I_emb=1, I_pos=2, I_l1s=3, I_l1b=4, I_wq=5, I_wk=6, I_wv=7,
      I_wo=8, I_l2s=9, I_l2b=10, I_w1=11, I_b1=12, I_w2=13, I_b2=14,
      I_lfs=15, I_lfb=16, I_wout=17, I_bout=18;
  if (in_sizes[0] != S){   // fallback: alphabetically sorted keys
    I_b1=0;  I_b2=1;  I_bout=2; I_emb=3;  I_l1b=4; I_l1s=5;  I_l2b=6;
    I_l2s=7; I_lfb=8; I_lfs=9;  I_pos=10; I_tok=11; I_w1=12; I_w2=13;
    I_wk=14; I_wo=15; I_wout=16; I_wq=17; I_wv=18;
  }

  const int*   tokens = (const int*)d_in[I_tok];
  const float* emb  = (const float*)d_in[I_emb];
  const float* pos  = (const float*)d_in[I_pos];
  const float* ln1s = (const float*)d_in[I_l1s];
  const float* ln1b = (const float*)d_in[I_l1b];
  const float* wq   = (const float*)d_in[I_wq];
  const float* wk   = (const float*)d_in[I_wk];
  const float* wv   = (const float*)d_in[I_wv];
  const float* wo   = (const float*)d_in[I_wo];
  const float* ln2s = (const float*)d_in[I_l2s];
  const float* ln2b = (const float*)d_in[I_l2b];
  const float* w1   = (const float*)d_in[I_w1];
  const float* b1   = (const float*)d_in[I_b1];
  const float* w2   = (const float*)d_in[I_w2];
  const float* b2   = (const float*)d_in[I_b2];
  const float* lnfs = (const float*)d_in[I_lfs];
  const float* lnfb = (const float*)d_in[I_lfb];
  const float* wout = (const float*)d_in[I_wout];
  const float* bout = (const float*)d_in[I_bout];
  float* outp = (float*)d_out;   // reference output dtype is float32

  // workspace (fp32, 24 MB):
  //   x @0 (4MB) | h @4MB (4MB) | q @8, k @12, v @16, o @20 (4MB each)
  //   g @8MB (16MB) overlays q/k/v/o (dead by MLP time)
  char* ws = (char*)d_ws;
  float* x  = (float*)(ws);
  float* h  = (float*)(ws + ((size_t)4  << 20));
  float* qb = (float*)(ws + ((size_t)8  << 20));
  float* kb = (float*)(ws + ((size_t)12 << 20));
  float* vb = (float*)(ws + ((size_t)16 << 20));
  float* ob = (float*)(ws + ((size_t)20 << 20));
  float* gb = (float*)(ws + ((size_t)8  << 20));

  k_embed<<<dim3(S), dim3(128), 0, stream>>>(tokens, emb, pos, x);

  for (int l = 0; l < NL; ++l){
    size_t wOff = (size_t)l * D * D;
    k_ln<<<dim3(S), dim3(64), 0, stream>>>(x, ln1s + (size_t)l * D, ln1b + (size_t)l * D, h);
    k_ngemm<0><<<dim3((D+255)/256, S/4), dim3(256), 0, stream>>>(
        h, wq + wOff, nullptr, qb, S, D, D, 0.125f);
    k_ngemm<0><<<dim3((D+255)/256, S/4), dim3(256), 0, stream>>>(
        h, wk + wOff, nullptr, kb, S, D, D, 1.f);
    k_ngemm<0><<<dim3((D+255)/256, S/4), dim3(256), 0, stream>>>(
        h, wv + wOff, nullptr, vb, S, D, D, 1.f);
    k_attn<<<dim3(H * S / 64), dim3(64), 0, stream>>>(qb, kb, vb, tokens, ob);
    k_ngemm<2><<<dim3((D+255)/256, S/4), dim3(256), 0, stream>>>(
        ob, wo + wOff, nullptr, x, S, D, D, 1.f);
    k_ln<<<dim3(S), dim3(64), 0, stream>>>(x, ln2s + (size_t)l * D, ln2b + (size_t)l * D, h);
    k_ngemm<1><<<dim3((MLPD+255)/256, S/4), dim3(256), 0, stream>>>(
        h, w1 + (size_t)l * D * MLPD, b1 + (size_t)l * MLPD, gb, S, MLPD, D, 1.f);
    k_ngemm<2><<<dim3((D+255)/256, S/4), dim3(256), 0, stream>>>(
        gb, w2 + (size_t)l * MLPD * D, b2 + (size_t)l * D, x, S, D, MLPD, 1.f);
  }

  k_ln<<<dim3(S), dim3(64), 0, stream>>>(x, lnfs, lnfb, h);
  k_ngemm<3><<<dim3((VOC+255)/256, S/4), dim3(256), 0, stream>>>(
      h, wout, bout, outp, S, VOC, D, 1.f);
}

// Round 5
// 4611.803 us; speedup vs baseline: 2.9447x; 2.9447x over previous
//
#include <hip/hip_runtime.h>
#include <hip/hip_bf16.h>
#include <cstdint>
#include <cstddef>

#define DEV __device__ __forceinline__

namespace {

constexpr int S    = 2048;
constexpr int D    = 512;
constexpr int H    = 8;
constexpr int DH   = 64;
constexpr int NL   = 6;
constexpr int MLPD = 2048;
constexpr int VOC  = 256;
constexpr int BLKA = 128;   // sparse attention block
constexpr int CCOL = 32;    // fixed2 column count
constexpr float EPSF = 1e-6f;

typedef unsigned short u16;
typedef __attribute__((ext_vector_type(8))) short s8v;   // 8 x bf16 (4 VGPR)
typedef __attribute__((ext_vector_type(4))) float f4v;   // MFMA accum

DEV float u2f(u16 u){
  union { unsigned int i; float f; } t; t.i = ((unsigned int)u) << 16; return t.f;
}
DEV short bfr(float f){
  __hip_bfloat16 h = __float2bfloat16(f);
  short s; __builtin_memcpy(&s, &h, 2); return s;
}
DEV float gelu_tanh(float x){
  float x3 = x * x * x;
  return 0.5f * x * (1.f + tanhf(0.7978845608028654f * (x + 0.044715f * x3)));
}

// ---------------- embedding + positional (shift-right teacher forcing) -------
__global__ void k_embed(const int* __restrict__ tokens, const float* __restrict__ emb,
                        const float* __restrict__ pos, float* __restrict__ x){
  int s = blockIdx.x;
  int tok = (s == 0) ? 0 : tokens[s - 1];
  if (tok < 0) tok = 0; if (tok >= VOC) tok = VOC - 1;
  const float* er = emb + (size_t)tok * D;
  const float* pr = pos + (size_t)s * D;
  float* xr = x + (size_t)s * D;
  for (int d = threadIdx.x; d < D; d += blockDim.x)
    xr[d] = er[d] + pr[d];
}

// ---------------- layernorm: one wave per row, fp32 in -> bf16 out -----------
__global__ __launch_bounds__(64)
void k_ln(const float* __restrict__ x, const float* __restrict__ sc,
          const float* __restrict__ bi, u16* __restrict__ out){
  int s = blockIdx.x, t = threadIdx.x;
  const float* xr = x + (size_t)s * D;
  float v[8]; float sum = 0.f, sq = 0.f;
  #pragma unroll
  for (int e = 0; e < 8; ++e){ v[e] = xr[t + 64 * e]; sum += v[e]; sq += v[e] * v[e]; }
  #pragma unroll
  for (int off = 32; off >= 1; off >>= 1){
    sum += __shfl_down(sum, off, 64);
    sq  += __shfl_down(sq,  off, 64);
  }
  sum = __shfl(sum, 0, 64); sq = __shfl(sq, 0, 64);
  float mu  = sum * (1.f / (float)D);
  float var = sq * (1.f / (float)D) - mu * mu;
  float r = rsqrtf(var + EPSF);
  u16* orow = out + (size_t)s * D;
  #pragma unroll
  for (int e = 0; e < 8; ++e){
    int d = t + 64 * e;
    orow[d] = (u16)bfr((v[e] - mu) * r * sc[d] + bi[d]);
  }
}

// ---------------- MFMA GEMM core: A bf16 [M,K], B fp32 [K,N] -> acc fp32 -----
// Tile 128x128, BK=32, 256 threads (4 waves, 2x2 of 64x64).
// LDS subtile layout: [kgroup g=k>>3][row][e=k&7], group stride 1032 shorts
// (2064 B = 2048 + 16 pad): staging writes and ds_read_b128 frag reads are
// conflict-free (+16B pad rotates banks by 4 per group).
constexpr int GSTR = 1032;   // shorts per k-group

DEV void mgemm_core(const u16* __restrict__ A, const float* __restrict__ B,
                    int N, int K, int m0, int n0,
                    short* __restrict__ As, short* __restrict__ Bs,
                    f4v (&acc)[4][4])
{
  const int t = threadIdx.x;
  const int wv = t >> 6, lane = t & 63;
  const int wr = wv >> 1, wc = wv & 1;
  const int lr = lane & 15, lg = lane >> 4;
  const int ar = t >> 2, ac = t & 3;        // A: row(0..63), kgroup
  const int bn = t & 127, bkh = t >> 7;     // B: col, k-half(0/1)

  for (int k0 = 0; k0 < K; k0 += 32){
    // global loads (A bf16 16B chunks; B fp32 scalar gather, coalesced per k-row)
    s8v av0 = *reinterpret_cast<const s8v*>(A + (size_t)(m0 + ar) * K + k0 + ac * 8);
    s8v av1 = *reinterpret_cast<const s8v*>(A + (size_t)(m0 + ar + 64) * K + k0 + ac * 8);
    float tb[16];
    #pragma unroll
    for (int kk = 0; kk < 16; ++kk)
      tb[kk] = B[(size_t)(k0 + bkh * 16 + kk) * N + n0 + bn];
    __syncthreads();
    *reinterpret_cast<s8v*>(&As[ac * GSTR + ar * 8]) = av0;
    *reinterpret_cast<s8v*>(&As[ac * GSTR + (ar + 64) * 8]) = av1;
    s8v p0, p1;
    #pragma unroll
    for (int e = 0; e < 8; ++e){ p0[e] = bfr(tb[e]); p1[e] = bfr(tb[8 + e]); }
    *reinterpret_cast<s8v*>(&Bs[(bkh * 2 + 0) * GSTR + bn * 8]) = p0;
    *reinterpret_cast<s8v*>(&Bs[(bkh * 2 + 1) * GSTR + bn * 8]) = p1;
    __syncthreads();
    s8v af[4], bf2[4];
    #pragma unroll
    for (int fi = 0; fi < 4; ++fi)
      af[fi] = *reinterpret_cast<const s8v*>(&As[lg * GSTR + (wr * 64 + fi * 16 + lr) * 8]);
    #pragma unroll
    for (int fj = 0; fj < 4; ++fj)
      bf2[fj] = *reinterpret_cast<const s8v*>(&Bs[lg * GSTR + (wc * 64 + fj * 16 + lr) * 8]);
    #pragma unroll
    for (int fi = 0; fi < 4; ++fi)
      #pragma unroll
      for (int fj = 0; fj < 4; ++fj)
        acc[fi][fj] = __builtin_amdgcn_mfma_f32_16x16x32_bf16(af[fi], bf2[fj], acc[fi][fj], 0, 0, 0);
  }
}

// MODE 0: Cb = bf16(acc*alpha)         MODE 1: Cb = bf16(gelu(acc+bias))
// MODE 2: Cf += acc (+bias)            MODE 3: Cf = acc + bias
template<int MODE>
__global__ __launch_bounds__(256)
void k_mgemm(const u16* __restrict__ A, const float* __restrict__ B,
             const float* __restrict__ bias, float* __restrict__ Cf,
             u16* __restrict__ Cb, int N, int K, float alpha)
{
  __shared__ __align__(16) short As[4 * GSTR];
  __shared__ __align__(16) short Bs[4 * GSTR];
  int n0 = blockIdx.x * 128, m0 = blockIdx.y * 128;
  f4v acc[4][4] = {};
  mgemm_core(A, B, N, K, m0, n0, As, Bs, acc);
  const int lane = threadIdx.x & 63, wv = threadIdx.x >> 6;
  const int wr = wv >> 1, wc = wv & 1, lr = lane & 15, lg = lane >> 4;
  #pragma unroll
  for (int fi = 0; fi < 4; ++fi)
    #pragma unroll
    for (int fj = 0; fj < 4; ++fj)
      #pragma unroll
      for (int r = 0; r < 4; ++r){
        int row = m0 + wr * 64 + fi * 16 + lg * 4 + r;
        int col = n0 + wc * 64 + fj * 16 + lr;
        size_t idx = (size_t)row * N + col;
        float v = acc[fi][fj][r] * alpha;
        if (MODE == 0)      Cb[idx] = (u16)bfr(v);
        else if (MODE == 1) Cb[idx] = (u16)bfr(gelu_tanh(v + bias[col]));
        else if (MODE == 2) Cf[idx] += v + (bias ? bias[col] : 0.f);
        else                Cf[idx] = v + bias[col];
      }
}

// fused q/k/v projection: blockIdx.z selects weight/output; q scaled by 1/8
__global__ __launch_bounds__(256)
void k_mgemm_qkv(const u16* __restrict__ A,
                 const float* __restrict__ B0, const float* __restrict__ B1,
                 const float* __restrict__ B2,
                 u16* __restrict__ C0, u16* __restrict__ C1, u16* __restrict__ C2,
                 int N, int K)
{
  __shared__ __align__(16) short As[4 * GSTR];
  __shared__ __align__(16) short Bs[4 * GSTR];
  const float* B = (blockIdx.z == 0) ? B0 : (blockIdx.z == 1 ? B1 : B2);
  u16*        C = (blockIdx.z == 0) ? C0 : (blockIdx.z == 1 ? C1 : C2);
  float alpha   = (blockIdx.z == 0) ? 0.125f : 1.f;
  int n0 = blockIdx.x * 128, m0 = blockIdx.y * 128;
  f4v acc[4][4] = {};
  mgemm_core(A, B, N, K, m0, n0, As, Bs, acc);
  const int lane = threadIdx.x & 63, wv = threadIdx.x >> 6;
  const int wr = wv >> 1, wc = wv & 1, lr = lane & 15, lg = lane >> 4;
  #pragma unroll
  for (int fi = 0; fi < 4; ++fi)
    #pragma unroll
    for (int fj = 0; fj < 4; ++fj)
      #pragma unroll
      for (int r = 0; r < 4; ++r){
        int row = m0 + wr * 64 + fi * 16 + lg * 4 + r;
        int col = n0 + wc * 64 + fj * 16 + lr;
        C[(size_t)row * N + col] = (u16)bfr(acc[fi][fj][r] * alpha);
      }
}

// ---------------- sparse attention: one WAVE per (head, query row) -----------
// lane = head-dim. K/V rows are coalesced 128B loads; dot via shfl_xor reduce;
// online softmax in per-lane scalars (wave-uniform).
__global__ __launch_bounds__(256)
void k_attn(const u16* __restrict__ q, const u16* __restrict__ kM,
            const u16* __restrict__ vM, const int* __restrict__ tokens,
            u16* __restrict__ o)
{
  int gw = blockIdx.x * 4 + (threadIdx.x >> 6);
  int lane = threadIdx.x & 63;
  int h0 = gw >> 11;          // / S
  int i  = gw & (S - 1);
  int col = h0 * DH + lane;
  float qv = u2f(q[(size_t)i * D + col]);
  float acc = 0.f, mrun = -1e30f, lrun = 0.f;
  int cnt = 0;
  int bi = i >> 7;
  for (int bj = 0; bj <= bi; ++bj){
    int j0 = bj * BLKA + ((bj < bi) ? (BLKA - CCOL) : 0);
    int j1 = (bj < bi) ? (bj * BLKA + BLKA) : (i + 1);
    for (int j = j0; j < j1; ++j){
      if (tokens[j] > 0){
        float p = qv * u2f(kM[(size_t)j * D + col]);
        #pragma unroll
        for (int off = 32; off >= 1; off >>= 1)
          p += __shfl_xor(p, off, 64);
        float mn = fmaxf(mrun, p);
        float c = __expf(mrun - mn);
        float e = __expf(p - mn);
        lrun = lrun * c + e;
        acc  = acc * c + e * u2f(vM[(size_t)j * D + col]);
        mrun = mn; ++cnt;
      }
    }
  }
  if (cnt == 0){
    acc = 0.f;
    for (int j = 0; j < S; ++j) acc += u2f(vM[(size_t)j * D + col]);
    lrun = (float)S;
  }
  o[(size_t)i * D + col] = (u16)bfr(acc / lrun);
}

} // anonymous namespace

extern "C" void kernel_launch(void* const* d_in, const int* in_sizes, int n_in,
                              void* d_out, int out_size, void* d_ws, size_t ws_size,
                              hipStream_t stream)
{
  (void)n_in; (void)out_size; (void)ws_size;

  int I_tok=0, I_emb=1, I_pos=2, I_l1s=3, I_l1b=4, I_wq=5, I_wk=6, I_wv=7,
      I_wo=8, I_l2s=9, I_l2b=10, I_w1=11, I_b1=12, I_w2=13, I_b2=14,
      I_lfs=15, I_lfb=16, I_wout=17, I_bout=18;
  if (in_sizes[0] != S){   // fallback: alphabetically sorted keys
    I_b1=0;  I_b2=1;  I_bout=2; I_emb=3;  I_l1b=4; I_l1s=5;  I_l2b=6;
    I_l2s=7; I_lfb=8; I_lfs=9;  I_pos=10; I_tok=11; I_w1=12; I_w2=13;
    I_wk=14; I_wo=15; I_wout=16; I_wq=17; I_wv=18;
  }

  const int*   tokens = (const int*)d_in[I_tok];
  const float* emb  = (const float*)d_in[I_emb];
  const float* pos  = (const float*)d_in[I_pos];
  const float* ln1s = (const float*)d_in[I_l1s];
  const float* ln1b = (const float*)d_in[I_l1b];
  const float* wq   = (const float*)d_in[I_wq];
  const float* wk   = (const float*)d_in[I_wk];
  const float* wv   = (const float*)d_in[I_wv];
  const float* wo   = (const float*)d_in[I_wo];
  const float* ln2s = (const float*)d_in[I_l2s];
  const float* ln2b = (const float*)d_in[I_l2b];
  const float* w1   = (const float*)d_in[I_w1];
  const float* b1   = (const float*)d_in[I_b1];
  const float* w2   = (const float*)d_in[I_w2];
  const float* b2   = (const float*)d_in[I_b2];
  const float* lnfs = (const float*)d_in[I_lfs];
  const float* lnfb = (const float*)d_in[I_lfb];
  const float* wout = (const float*)d_in[I_wout];
  const float* bout = (const float*)d_in[I_bout];
  float* outp = (float*)d_out;   // reference output dtype is float32

  // workspace (22 MB):
  //   x    fp32 @ 0    (4 MB)  residual stream
  //   hb   bf16 @ 4 MB (2 MB)  LN output
  //   qb   bf16 @ 6 MB (2 MB)
  //   kb   bf16 @ 8 MB (2 MB)
  //   vb   bf16 @10 MB (2 MB)
  //   ob   bf16 @12 MB (2 MB)  attention output
  //   gb   bf16 @14 MB (8 MB)  gelu output
  char* ws = (char*)d_ws;
  float* x  = (float*)(ws);
  u16*   hb = (u16*)(ws + ((size_t)4  << 20));
  u16*   qb = (u16*)(ws + ((size_t)6  << 20));
  u16*   kb = (u16*)(ws + ((size_t)8  << 20));
  u16*   vb = (u16*)(ws + ((size_t)10 << 20));
  u16*   ob = (u16*)(ws + ((size_t)12 << 20));
  u16*   gb = (u16*)(ws + ((size_t)14 << 20));

  k_embed<<<dim3(S), dim3(128), 0, stream>>>(tokens, emb, pos, x);

  for (int l = 0; l < NL; ++l){
    size_t wOff = (size_t)l * D * D;
    k_ln<<<dim3(S), dim3(64), 0, stream>>>(x, ln1s + (size_t)l * D, ln1b + (size_t)l * D, hb);
    k_mgemm_qkv<<<dim3(D / 128, S / 128, 3), dim3(256), 0, stream>>>(
        hb, wq + wOff, wk + wOff, wv + wOff, qb, kb, vb, D, D);
    k_attn<<<dim3(H * S / 4), dim3(256), 0, stream>>>(qb, kb, vb, tokens, ob);
    k_mgemm<2><<<dim3(D / 128, S / 128), dim3(256), 0, stream>>>(
        ob, wo + wOff, nullptr, x, nullptr, D, D, 1.f);
    k_ln<<<dim3(S), dim3(64), 0, stream>>>(x, ln2s + (size_t)l * D, ln2b + (size_t)l * D, hb);
    k_mgemm<1><<<dim3(MLPD / 128, S / 128), dim3(256), 0, stream>>>(
        hb, w1 + (size_t)l * D * MLPD, b1 + (size_t)l * MLPD, nullptr, gb, MLPD, D, 1.f);
    k_mgemm<2><<<dim3(D / 128, S / 128), dim3(256), 0, stream>>>(
        gb, w2 + (size_t)l * MLPD * D, b2 + (size_t)l * D, x, nullptr, D, MLPD, 1.f);
  }

  k_ln<<<dim3(S), dim3(64), 0, stream>>>(x, lnfs, lnfb, hb);
  k_mgemm<3><<<dim3(VOC / 128, S / 128), dim3(256), 0, stream>>>(
      hb, wout, bout, outp, nullptr, VOC, D, 1.f);
}

// Round 7
// 1591.817 us; speedup vs baseline: 8.5313x; 2.8972x over previous
//
#include <hip/hip_runtime.h>
#include <hip/hip_bf16.h>
#include <cstdint>
#include <cstddef>

#define DEV __device__ __forceinline__

namespace {

constexpr int S    = 2048;
constexpr int D    = 512;
constexpr int H    = 8;
constexpr int DH   = 64;
constexpr int NL   = 6;
constexpr int MLPD = 2048;
constexpr int VOC  = 256;
constexpr float EPSF = 1e-6f;

typedef unsigned short u16;
typedef __attribute__((ext_vector_type(8))) short s8v;   // 8 x bf16 (4 VGPR)
typedef __attribute__((ext_vector_type(4))) float f4v;   // MFMA accum

DEV float u2f(u16 u){
  union { unsigned int i; float f; } t; t.i = ((unsigned int)u) << 16; return t.f;
}
DEV short bfr(float f){
  __hip_bfloat16 h = __float2bfloat16(f);
  short s; __builtin_memcpy(&s, &h, 2); return s;
}
DEV float gelu_tanh(float x){
  float x3 = x * x * x;
  return 0.5f * x * (1.f + tanhf(0.7978845608028654f * (x + 0.044715f * x3)));
}

// ---------------- embedding + positional (shift-right teacher forcing) -------
__global__ void k_embed(const int* __restrict__ tokens, const float* __restrict__ emb,
                        const float* __restrict__ pos, float* __restrict__ x){
  int s = blockIdx.x;
  int tok = (s == 0) ? 0 : tokens[s - 1];
  if (tok < 0) tok = 0; if (tok >= VOC) tok = VOC - 1;
  const float* er = emb + (size_t)tok * D;
  const float* pr = pos + (size_t)s * D;
  float* xr = x + (size_t)s * D;
  for (int d = threadIdx.x; d < D; d += blockDim.x)
    xr[d] = er[d] + pr[d];
}

// ---------------- layernorm: one wave per row, fp32 in -> bf16 out -----------
__global__ __launch_bounds__(64)
void k_ln(const float* __restrict__ x, const float* __restrict__ sc,
          const float* __restrict__ bi, u16* __restrict__ out){
  int s = blockIdx.x, t = threadIdx.x;
  const float* xr = x + (size_t)s * D;
  float v[8]; float sum = 0.f, sq = 0.f;
  #pragma unroll
  for (int e = 0; e < 8; ++e){ v[e] = xr[t + 64 * e]; sum += v[e]; sq += v[e] * v[e]; }
  #pragma unroll
  for (int off = 32; off >= 1; off >>= 1){
    sum += __shfl_down(sum, off, 64);
    sq  += __shfl_down(sq,  off, 64);
  }
  sum = __shfl(sum, 0, 64); sq = __shfl(sq, 0, 64);
  float mu  = sum * (1.f / (float)D);
  float var = sq * (1.f / (float)D) - mu * mu;
  float r = rsqrtf(var + EPSF);
  u16* orow = out + (size_t)s * D;
  #pragma unroll
  for (int e = 0; e < 8; ++e){
    int d = t + 64 * e;
    orow[d] = (u16)bfr((v[e] - mu) * r * sc[d] + bi[d]);
  }
}

// ---------------- MFMA GEMM (verified round 5) --------------------------------
constexpr int GSTR = 1032;   // shorts per k-group

DEV void mgemm_core(const u16* __restrict__ A, const float* __restrict__ B,
                    int N, int K, int m0, int n0,
                    short* __restrict__ As, short* __restrict__ Bs,
                    f4v (&acc)[4][4])
{
  const int t = threadIdx.x;
  const int wv = t >> 6, lane = t & 63;
  const int wr = wv >> 1, wc = wv & 1;
  const int lr = lane & 15, lg = lane >> 4;
  const int ar = t >> 2, ac = t & 3;
  const int bn = t & 127, bkh = t >> 7;

  for (int k0 = 0; k0 < K; k0 += 32){
    s8v av0 = *reinterpret_cast<const s8v*>(A + (size_t)(m0 + ar) * K + k0 + ac * 8);
    s8v av1 = *reinterpret_cast<const s8v*>(A + (size_t)(m0 + ar + 64) * K + k0 + ac * 8);
    float tb[16];
    #pragma unroll
    for (int kk = 0; kk < 16; ++kk)
      tb[kk] = B[(size_t)(k0 + bkh * 16 + kk) * N + n0 + bn];
    __syncthreads();
    *reinterpret_cast<s8v*>(&As[ac * GSTR + ar * 8]) = av0;
    *reinterpret_cast<s8v*>(&As[ac * GSTR + (ar + 64) * 8]) = av1;
    s8v p0, p1;
    #pragma unroll
    for (int e = 0; e < 8; ++e){ p0[e] = bfr(tb[e]); p1[e] = bfr(tb[8 + e]); }
    *reinterpret_cast<s8v*>(&Bs[(bkh * 2 + 0) * GSTR + bn * 8]) = p0;
    *reinterpret_cast<s8v*>(&Bs[(bkh * 2 + 1) * GSTR + bn * 8]) = p1;
    __syncthreads();
    s8v af[4], bf2[4];
    #pragma unroll
    for (int fi = 0; fi < 4; ++fi)
      af[fi] = *reinterpret_cast<const s8v*>(&As[lg * GSTR + (wr * 64 + fi * 16 + lr) * 8]);
    #pragma unroll
    for (int fj = 0; fj < 4; ++fj)
      bf2[fj] = *reinterpret_cast<const s8v*>(&Bs[lg * GSTR + (wc * 64 + fj * 16 + lr) * 8]);
    #pragma unroll
    for (int fi = 0; fi < 4; ++fi)
      #pragma unroll
      for (int fj = 0; fj < 4; ++fj)
        acc[fi][fj] = __builtin_amdgcn_mfma_f32_16x16x32_bf16(af[fi], bf2[fj], acc[fi][fj], 0, 0, 0);
  }
}

template<int MODE>
__global__ __launch_bounds__(256)
void k_mgemm(const u16* __restrict__ A, const float* __restrict__ B,
             const float* __restrict__ bias, float* __restrict__ Cf,
             u16* __restrict__ Cb, int N, int K, float alpha)
{
  __shared__ __align__(16) short As[4 * GSTR];
  __shared__ __align__(16) short Bs[4 * GSTR];
  int n0 = blockIdx.x * 128, m0 = blockIdx.y * 128;
  f4v acc[4][4] = {};
  mgemm_core(A, B, N, K, m0, n0, As, Bs, acc);
  const int lane = threadIdx.x & 63, wv = threadIdx.x >> 6;
  const int wr = wv >> 1, wc = wv & 1, lr = lane & 15, lg = lane >> 4;
  #pragma unroll
  for (int fi = 0; fi < 4; ++fi)
    #pragma unroll
    for (int fj = 0; fj < 4; ++fj)
      #pragma unroll
      for (int r = 0; r < 4; ++r){
        int row = m0 + wr * 64 + fi * 16 + lg * 4 + r;
        int col = n0 + wc * 64 + fj * 16 + lr;
        size_t idx = (size_t)row * N + col;
        float v = acc[fi][fj][r] * alpha;
        if (MODE == 0)      Cb[idx] = (u16)bfr(v);
        else if (MODE == 1) Cb[idx] = (u16)bfr(gelu_tanh(v + bias[col]));
        else if (MODE == 2) Cf[idx] += v + (bias ? bias[col] : 0.f);
        else                Cf[idx] = v + bias[col];
      }
}

__global__ __launch_bounds__(256)
void k_mgemm_qkv(const u16* __restrict__ A,
                 const float* __restrict__ B0, const float* __restrict__ B1,
                 const float* __restrict__ B2,
                 u16* __restrict__ C0, u16* __restrict__ C1, u16* __restrict__ C2,
                 int N, int K)
{
  __shared__ __align__(16) short As[4 * GSTR];
  __shared__ __align__(16) short Bs[4 * GSTR];
  const float* B = (blockIdx.z == 0) ? B0 : (blockIdx.z == 1 ? B1 : B2);
  u16*        C = (blockIdx.z == 0) ? C0 : (blockIdx.z == 1 ? C1 : C2);
  float alpha   = (blockIdx.z == 0) ? 0.125f : 1.f;
  int n0 = blockIdx.x * 128, m0 = blockIdx.y * 128;
  f4v acc[4][4] = {};
  mgemm_core(A, B, N, K, m0, n0, As, Bs, acc);
  const int lane = threadIdx.x & 63, wv = threadIdx.x >> 6;
  const int wr = wv >> 1, wc = wv & 1, lr = lane & 15, lg = lane >> 4;
  #pragma unroll
  for (int fi = 0; fi < 4; ++fi)
    #pragma unroll
    for (int fj = 0; fj < 4; ++fj)
      #pragma unroll
      for (int r = 0; r < 4; ++r){
        int row = m0 + wr * 64 + fi * 16 + lg * 4 + r;
        int col = n0 + wc * 64 + fj * 16 + lr;
        C[(size_t)row * N + col] = (u16)bfr(acc[fi][fj][r] * alpha);
      }
}

// ---------------- V column mean (fallback for fully-masked rows) -------------
__global__ __launch_bounds__(256)
void k_vmean(const u16* __restrict__ vb, float* __restrict__ vmean){
  int c = blockIdx.x * 256 + threadIdx.x;   // grid 2 -> 512 cols
  float s = 0.f;
  for (int j = 0; j < S; j += 8){
    #pragma unroll
    for (int e = 0; e < 8; ++e) s += u2f(vb[(size_t)(j + e) * D + c]);
  }
  vmean[c] = s * (1.f / (float)S);
}

// ---------------- MFMA block-sparse flash attention --------------------------
// grid (S/64, H); 4 waves/block; wave w owns q-rows q0+16w..+15.
// BUGFIX vs round 6: l[] is a per-lane PARTIAL softmax denominator (2 keys per
// lane); the epilogue now xor-reduces it across the 16-lane column group
// before normalizing. Numerator o* was always the full MFMA row sum.
__global__ __launch_bounds__(256)
void k_mattn(const u16* __restrict__ qb, const u16* __restrict__ kb,
             const u16* __restrict__ vb, const int* __restrict__ tokens,
             const float* __restrict__ vmean, u16* __restrict__ ob)
{
  const int q0 = blockIdx.x * 64;
  const int h  = blockIdx.y;
  const int B  = q0 >> 7;
  const int half = (q0 >> 6) & 1;
  const int t = threadIdx.x, w = t >> 6, lane = t & 63;
  const int lr = lane & 15, lg = lane >> 4;

  __shared__ __align__(16) u16 Vt[64][40];       // V^T tile (+pad, 80B rows)
  __shared__ __align__(16) u16 Ps[4][16][40];    // per-wave P tile

  const u16* qrow = qb + (size_t)(q0 + 16 * w + lr) * D + h * DH;
  s8v qf0 = *reinterpret_cast<const s8v*>(qrow + lg * 8);
  s8v qf1 = *reinterpret_cast<const s8v*>(qrow + 32 + lg * 8);

  f4v o0 = {}, o1 = {}, o2 = {}, o3 = {};
  float m[4] = {-1e30f, -1e30f, -1e30f, -1e30f};
  float l[4] = {0.f, 0.f, 0.f, 0.f};

  const int vkey = t & 31, vdq = (t >> 5) * 8;
  const int ntiles = B + (half ? 4 : 2);

  for (int tt = 0; tt < ntiles; ++tt){
    int kbase; bool causal;
    if (tt < B){ kbase = tt * 128 + 96; causal = false; }
    else       { kbase = B * 128 + (tt - B) * 32; causal = (kbase >= q0); }

    __syncthreads();
    s8v vv = *reinterpret_cast<const s8v*>(vb + (size_t)(kbase + vkey) * D + h * DH + vdq);
    #pragma unroll
    for (int e = 0; e < 8; ++e) Vt[vdq + e][vkey] = (u16)vv[e];
    __syncthreads();

    f4v s0 = {}, s1 = {};
    const u16* k0p = kb + (size_t)(kbase + lr) * D + h * DH;
    const u16* k1p = kb + (size_t)(kbase + 16 + lr) * D + h * DH;
    s8v kf;
    kf = *reinterpret_cast<const s8v*>(k0p + lg * 8);
    s0 = __builtin_amdgcn_mfma_f32_16x16x32_bf16(qf0, kf, s0, 0, 0, 0);
    kf = *reinterpret_cast<const s8v*>(k0p + 32 + lg * 8);
    s0 = __builtin_amdgcn_mfma_f32_16x16x32_bf16(qf1, kf, s0, 0, 0, 0);
    kf = *reinterpret_cast<const s8v*>(k1p + lg * 8);
    s1 = __builtin_amdgcn_mfma_f32_16x16x32_bf16(qf0, kf, s1, 0, 0, 0);
    kf = *reinterpret_cast<const s8v*>(k1p + 32 + lg * 8);
    s1 = __builtin_amdgcn_mfma_f32_16x16x32_bf16(qf1, kf, s1, 0, 0, 0);

    const int tok0 = tokens[kbase + lr] > 0;
    const int tok1 = tokens[kbase + 16 + lr] > 0;
    #pragma unroll
    for (int r = 0; r < 4; ++r){
      int qg = q0 + 16 * w + 4 * lg + r;
      float a0 = (tok0 && (!causal || kbase + lr <= qg))      ? s0[r] : -1e30f;
      float a1 = (tok1 && (!causal || kbase + 16 + lr <= qg)) ? s1[r] : -1e30f;
      float tm = fmaxf(a0, a1);
      tm = fmaxf(tm, __shfl_xor(tm, 1, 64));
      tm = fmaxf(tm, __shfl_xor(tm, 2, 64));
      tm = fmaxf(tm, __shfl_xor(tm, 4, 64));
      tm = fmaxf(tm, __shfl_xor(tm, 8, 64));
      float mn = fmaxf(m[r], tm);
      bool dead = (mn <= -1e29f);
      float sc = dead ? 1.f : __expf(m[r] - mn);
      float p0 = dead ? 0.f : __expf(a0 - mn);
      float p1 = dead ? 0.f : __expf(a1 - mn);
      l[r] = l[r] * sc + p0 + p1;   // per-lane partial; reduced in epilogue
      m[r] = mn;
      o0[r] *= sc; o1[r] *= sc; o2[r] *= sc; o3[r] *= sc;
      Ps[w][4 * lg + r][lr]      = (u16)bfr(p0);
      Ps[w][4 * lg + r][16 + lr] = (u16)bfr(p1);
    }

    asm volatile("s_waitcnt lgkmcnt(0)" ::: "memory");
    __builtin_amdgcn_sched_barrier(0);
    s8v pf  = *reinterpret_cast<const s8v*>(&Ps[w][lr][lg * 8]);
    s8v vf0 = *reinterpret_cast<const s8v*>(&Vt[lr][lg * 8]);
    s8v vf1 = *reinterpret_cast<const s8v*>(&Vt[16 + lr][lg * 8]);
    s8v vf2 = *reinterpret_cast<const s8v*>(&Vt[32 + lr][lg * 8]);
    s8v vf3 = *reinterpret_cast<const s8v*>(&Vt[48 + lr][lg * 8]);
    o0 = __builtin_amdgcn_mfma_f32_16x16x32_bf16(pf, vf0, o0, 0, 0, 0);
    o1 = __builtin_amdgcn_mfma_f32_16x16x32_bf16(pf, vf1, o1, 0, 0, 0);
    o2 = __builtin_amdgcn_mfma_f32_16x16x32_bf16(pf, vf2, o2, 0, 0, 0);
    o3 = __builtin_amdgcn_mfma_f32_16x16x32_bf16(pf, vf3, o3, 0, 0, 0);
  }

  // epilogue: reduce the partial softmax denominator across the 16-lane
  // column group (row 4lg+r lives on lanes lg*16..lg*16+15), then normalize.
  #pragma unroll
  for (int r = 0; r < 4; ++r){
    float lt = l[r];
    lt += __shfl_xor(lt, 1, 64);
    lt += __shfl_xor(lt, 2, 64);
    lt += __shfl_xor(lt, 4, 64);
    lt += __shfl_xor(lt, 8, 64);
    int qg = q0 + 16 * w + 4 * lg + r;
    u16* orow = ob + (size_t)qg * D + h * DH;
    bool dead = (lt <= 0.f);
    float inv = dead ? 0.f : 1.f / lt;
    orow[lr]      = (u16)bfr(dead ? vmean[h * DH + lr]      : o0[r] * inv);
    orow[16 + lr] = (u16)bfr(dead ? vmean[h * DH + 16 + lr] : o1[r] * inv);
    orow[32 + lr] = (u16)bfr(dead ? vmean[h * DH + 32 + lr] : o2[r] * inv);
    orow[48 + lr] = (u16)bfr(dead ? vmean[h * DH + 48 + lr] : o3[r] * inv);
  }
}

} // anonymous namespace

extern "C" void kernel_launch(void* const* d_in, const int* in_sizes, int n_in,
                              void* d_out, int out_size, void* d_ws, size_t ws_size,
                              hipStream_t stream)
{
  (void)n_in; (void)out_size; (void)ws_size;

  int I_tok=0, I_emb=1, I_pos=2, I_l1s=3, I_l1b=4, I_wq=5, I_wk=6, I_wv=7,
      I_wo=8, I_l2s=9, I_l2b=10, I_w1=11, I_b1=12, I_w2=13, I_b2=14,
      I_lfs=15, I_lfb=16, I_wout=17, I_bout=18;
  if (in_sizes[0] != S){   // fallback: alphabetically sorted keys
    I_b1=0;  I_b2=1;  I_bout=2; I_emb=3;  I_l1b=4; I_l1s=5;  I_l2b=6;
    I_l2s=7; I_lfb=8; I_lfs=9;  I_pos=10; I_tok=11; I_w1=12; I_w2=13;
    I_wk=14; I_wo=15; I_wout=16; I_wq=17; I_wv=18;
  }

  const int*   tokens = (const int*)d_in[I_tok];
  const float* emb  = (const float*)d_in[I_emb];
  const float* pos  = (const float*)d_in[I_pos];
  const float* ln1s = (const float*)d_in[I_l1s];
  const float* ln1b = (const float*)d_in[I_l1b];
  const float* wq   = (const float*)d_in[I_wq];
  const float* wk   = (const float*)d_in[I_wk];
  const float* wv   = (const float*)d_in[I_wv];
  const float* wo   = (const float*)d_in[I_wo];
  const float* ln2s = (const float*)d_in[I_l2s];
  const float* ln2b = (const float*)d_in[I_l2b];
  const float* w1   = (const float*)d_in[I_w1];
  const float* b1   = (const float*)d_in[I_b1];
  const float* w2   = (const float*)d_in[I_w2];
  const float* b2   = (const float*)d_in[I_b2];
  const float* lnfs = (const float*)d_in[I_lfs];
  const float* lnfb = (const float*)d_in[I_lfb];
  const float* wout = (const float*)d_in[I_wout];
  const float* bout = (const float*)d_in[I_bout];
  float* outp = (float*)d_out;   // reference output dtype is float32

  char* ws = (char*)d_ws;
  float* x  = (float*)(ws);
  u16*   hb = (u16*)(ws + ((size_t)4  << 20));
  u16*   qb = (u16*)(ws + ((size_t)6  << 20));
  u16*   kb = (u16*)(ws + ((size_t)8  << 20));
  u16*   vb = (u16*)(ws + ((size_t)10 << 20));
  u16*   ob = (u16*)(ws + ((size_t)12 << 20));
  u16*   gb = (u16*)(ws + ((size_t)14 << 20));
  float* vmean = (float*)(ws + ((size_t)22 << 20));

  k_embed<<<dim3(S), dim3(128), 0, stream>>>(tokens, emb, pos, x);

  for (int l = 0; l < NL; ++l){
    size_t wOff = (size_t)l * D * D;
    k_ln<<<dim3(S), dim3(64), 0, stream>>>(x, ln1s + (size_t)l * D, ln1b + (size_t)l * D, hb);
    k_mgemm_qkv<<<dim3(D / 128, S / 128, 3), dim3(256), 0, stream>>>(
        hb, wq + wOff, wk + wOff, wv + wOff, qb, kb, vb, D, D);
    k_vmean<<<dim3(2), dim3(256), 0, stream>>>(vb, vmean);
    k_mattn<<<dim3(S / 64, H), dim3(256), 0, stream>>>(qb, kb, vb, tokens, vmean, ob);
    k_mgemm<2><<<dim3(D / 128, S / 128), dim3(256), 0, stream>>>(
        ob, wo + wOff, nullptr, x, nullptr, D, D, 1.f);
    k_ln<<<dim3(S), dim3(64), 0, stream>>>(x, ln2s + (size_t)l * D, ln2b + (size_t)l * D, hb);
    k_mgemm<1><<<dim3(MLPD / 128, S / 128), dim3(256), 0, stream>>>(
        hb, w1 + (size_t)l * D * MLPD, b1 + (size_t)l * MLPD, nullptr, gb, MLPD, D, 1.f);
    k_mgemm<2><<<dim3(D / 128, S / 128), dim3(256), 0, stream>>>(
        gb, w2 + (size_t)l * MLPD * D, b2 + (size_t)l * D, x, nullptr, D, MLPD, 1.f);
  }

  k_ln<<<dim3(S), dim3(64), 0, stream>>>(x, lnfs, lnfb, hb);
  k_mgemm<3><<<dim3(VOC / 128, S / 128), dim3(256), 0, stream>>>(
      hb, wout, bout, outp, nullptr, VOC, D, 1.f);
}